// Round 1
// baseline (1401.507 us; speedup 1.0000x reference)
//
#include <hip/hip_runtime.h>
#include <hip/hip_bf16.h>

typedef __bf16 bf16_t;
typedef __bf16 bf16x8 __attribute__((ext_vector_type(8)));
typedef float f32x4 __attribute__((ext_vector_type(4)));

#define BM 128
#define BN 128
#define BK 32

#define GLOAD_LDS16(g, l)                                                      \
  __builtin_amdgcn_global_load_lds(                                            \
      (const __attribute__((address_space(1))) void*)(g),                      \
      (__attribute__((address_space(3))) void*)(l), 16, 0, 0)

// C[M][Nc] = A[M][Kd] * Bt[Nc][Kd]^T, all bf16 inputs, f32 accum.
// mode 0: write WxOut = bf16(acc), Unext = bf16(acc)            (Wx GEMM, z0=0)
// mode 1: u = Z + WxIn; zn = soft_thresh(u - acc); Z = zn; Unext = bf16(zn + WxIn)
__global__ __launch_bounds__(256) void gemm_bt_kernel(
    const bf16_t* __restrict__ A, const bf16_t* __restrict__ Bt,
    int M, int Nc, int Kd, int mode,
    const bf16_t* __restrict__ WxIn, float* __restrict__ Z,
    bf16_t* __restrict__ Unext, bf16_t* __restrict__ WxOut,
    const float* __restrict__ thresh_p)
{
  __shared__ __align__(16) bf16_t sA[BM * BK];
  __shared__ __align__(16) bf16_t sB[BN * BK];
  const int tid  = threadIdx.x;
  const int wid  = tid >> 6;
  const int lane = tid & 63;
  const int tileN = blockIdx.x * BN;   // x = col tiles (8) -> co-scheduled share A panel
  const int tileM = blockIdx.y * BM;   // y = row tiles (256)
  const int wm = (wid >> 1) * 64;      // wave 2x2 over 128x128, each 64x64
  const int wn = (wid & 1) * 64;
  const int lr = lane & 15;            // A row / B col within fragment
  const int kg = lane >> 4;            // k-group (8 elems)

  f32x4 acc[4][4] = {};

  for (int k0 = 0; k0 < Kd; k0 += BK) {
    __syncthreads();  // previous iter's LDS reads done
    #pragma unroll
    for (int j = 0; j < 2; ++j) {
      const int chunk = j * 4 + wid;              // 0..7, wave-uniform
      const int base  = (chunk << 6) + lane;      // 0..511
      const int row   = base >> 2;                // 0..127
      const int kc    = base & 3;                 // 16B chunk within 64B row
      const bf16_t* ga = A  + (size_t)(tileM + row) * Kd + k0 + kc * 8;
      const bf16_t* gb = Bt + (size_t)(tileN + row) * Kd + k0 + kc * 8;
      GLOAD_LDS16(ga, sA + ((size_t)chunk << 9));
      GLOAD_LDS16(gb, sB + ((size_t)chunk << 9));
    }
    __syncthreads();  // drains vmcnt + lgkmcnt

    bf16x8 af[4], bfr[4];
    #pragma unroll
    for (int mi = 0; mi < 4; ++mi)
      af[mi] = *reinterpret_cast<const bf16x8*>(sA + (wm + mi * 16 + lr) * BK + kg * 8);
    #pragma unroll
    for (int ni = 0; ni < 4; ++ni)
      bfr[ni] = *reinterpret_cast<const bf16x8*>(sB + (wn + ni * 16 + lr) * BK + kg * 8);
    #pragma unroll
    for (int mi = 0; mi < 4; ++mi)
      #pragma unroll
      for (int ni = 0; ni < 4; ++ni)
        acc[mi][ni] = __builtin_amdgcn_mfma_f32_16x16x32_bf16(af[mi], bfr[ni], acc[mi][ni], 0, 0, 0);
  }

  const float th = *thresh_p;
  #pragma unroll
  for (int mi = 0; mi < 4; ++mi) {
    #pragma unroll
    for (int ni = 0; ni < 4; ++ni) {
      const int row0 = tileM + wm + mi * 16 + kg * 4;  // C row = (lane>>4)*4 + r
      const int col  = tileN + wn + ni * 16 + lr;      // C col = lane&15
      #pragma unroll
      for (int r = 0; r < 4; ++r) {
        const size_t idx = (size_t)(row0 + r) * (size_t)Nc + col;
        const float v = acc[mi][ni][r];
        if (mode == 0) {
          const bf16_t w = (bf16_t)v;
          WxOut[idx] = w;
          Unext[idx] = w;         // u1 = 0 + Wx
        } else {
          const float wx = (float)WxIn[idx];
          const float u  = Z[idx] + wx;
          const float t  = u - v;
          const float a  = fabsf(t) - th;
          const float zn = (a > 0.f) ? copysignf(a, t) : 0.f;
          Z[idx] = zn;
          Unext[idx] = (bf16_t)(zn + wx);
        }
      }
    }
  }
}

__global__ void cast_f32_bf16_kernel(const float* __restrict__ src,
                                     bf16_t* __restrict__ dst, int n) {
  int i = blockIdx.x * blockDim.x + threadIdx.x;
  if (i < n) dst[i] = (bf16_t)src[i];
}

// x [B][C=512][P=1024] f32 -> xt [b*1024+p][c] bf16  (32x32 tiled transpose)
__global__ void transpose_cast_x_kernel(const float* __restrict__ x,
                                        bf16_t* __restrict__ xt) {
  __shared__ float t[32][33];
  const int b  = blockIdx.z;
  const int p0 = blockIdx.x * 32;
  const int c0 = blockIdx.y * 32;
  const int tx = threadIdx.x, ty = threadIdx.y;
  #pragma unroll
  for (int i = 0; i < 32; i += 8)
    t[ty + i][tx] = x[((size_t)b * 512 + c0 + ty + i) * 1024 + p0 + tx];
  __syncthreads();
  #pragma unroll
  for (int i = 0; i < 32; i += 8)
    xt[((size_t)b * 1024 + p0 + ty + i) * 512 + c0 + tx] = (bf16_t)t[tx][ty + i];
}

// zt [n=b*1024+p][k] f32 -> out[b*1048576 + k*1024 + p]
__global__ void transpose_out_kernel(const float* __restrict__ zt,
                                     float* __restrict__ out) {
  __shared__ float t[32][33];
  const int b  = blockIdx.z;
  const int p0 = blockIdx.x * 32;
  const int k0 = blockIdx.y * 32;
  const int tx = threadIdx.x, ty = threadIdx.y;
  #pragma unroll
  for (int i = 0; i < 32; i += 8)
    t[ty + i][tx] = zt[((size_t)b * 1024 + p0 + ty + i) * 1024 + k0 + tx]; // t[p][k]
  __syncthreads();
  #pragma unroll
  for (int i = 0; i < 32; i += 8)
    out[(size_t)b * 1048576 + (size_t)(k0 + ty + i) * 1024 + p0 + tx] = t[tx][ty + i];
}

__global__ void dict_norm_kernel(const float* __restrict__ dict,
                                 float* __restrict__ out) {
  const int row = blockIdx.x;       // 1024
  const int tid = threadIdx.x;      // 256
  const float* r = dict + (size_t)row * 512;
  float s = 0.f;
  for (int i = tid; i < 512; i += 256) { float v = r[i]; s += v * v; }
  #pragma unroll
  for (int off = 32; off > 0; off >>= 1) s += __shfl_down(s, off);
  __shared__ float ps[4];
  if ((tid & 63) == 0) ps[tid >> 6] = s;
  __syncthreads();
  const float inv = 1.0f / sqrtf(ps[0] + ps[1] + ps[2] + ps[3]);
  for (int i = tid; i < 512; i += 256) out[(size_t)row * 512 + i] = r[i] * inv;
}

extern "C" void kernel_launch(void* const* d_in, const int* in_sizes, int n_in,
                              void* d_out, int out_size, void* d_ws, size_t ws_size,
                              hipStream_t stream) {
  const float* x      = (const float*)d_in[0];  // [32,512,32,32]
  const float* dict   = (const float*)d_in[1];  // [1024,512]
  const float* W      = (const float*)d_in[2];  // [1024,512]
  const float* S      = (const float*)d_in[3];  // [1024,1024]
  const float* thresh = (const float*)d_in[4];  // scalar
  // d_in[5] = num_steps (5, fixed by setup)

  float* out = (float*)d_out;

  char* ws = (char*)d_ws;
  float*  zt   = (float*)ws;                      // 134,217,728 B  [32768][1024] f32
  bf16_t* WxBf = (bf16_t*)(ws + 134217728);       //  67,108,864 B  [32768][1024] bf16
  bf16_t* xt   = (bf16_t*)(ws + 201326592);       //  33,554,432 B  [32768][512]  bf16
  bf16_t* Wbf  = (bf16_t*)(ws + 234881024);       //   1,048,576 B
  bf16_t* Sbf  = (bf16_t*)(ws + 235929600);       //   2,097,152 B (end 238,026,752)

  // u ping-pong lives in d_out's z-region (fully overwritten by transpose_out)
  bf16_t* uA = (bf16_t*)out;                      // 67,108,864 B
  bf16_t* uB = uA + 33554432;                     // 67,108,864 B
  float* dnorm = out + 33554432;                  // dict_norm region (disjoint)

  hipMemsetAsync(zt, 0, 134217728, stream);
  cast_f32_bf16_kernel<<<dim3(2048), dim3(256), 0, stream>>>(W, Wbf, 524288);
  cast_f32_bf16_kernel<<<dim3(4096), dim3(256), 0, stream>>>(S, Sbf, 1048576);
  transpose_cast_x_kernel<<<dim3(32, 16, 32), dim3(32, 8), 0, stream>>>(x, xt);
  dict_norm_kernel<<<dim3(1024), dim3(256), 0, stream>>>(dict, dnorm);

  // Wx_t = x_t @ W^T  (writes WxBf + uA)
  gemm_bt_kernel<<<dim3(8, 256), dim3(256), 0, stream>>>(
      xt, Wbf, 32768, 1024, 512, 0, nullptr, nullptr, uA, WxBf, thresh);

  bf16_t* uc = uA; bf16_t* un = uB;
  for (int s = 0; s < 5; ++s) {
    gemm_bt_kernel<<<dim3(8, 256), dim3(256), 0, stream>>>(
        uc, Sbf, 32768, 1024, 1024, 1, WxBf, zt, un, nullptr, thresh);
    bf16_t* tmp = uc; uc = un; un = tmp;
  }

  transpose_out_kernel<<<dim3(32, 32, 32), dim3(32, 8), 0, stream>>>(zt, out);
}

// Round 2
// 634.992 us; speedup vs baseline: 2.2071x; 2.2071x over previous
//
#include <hip/hip_runtime.h>
#include <hip/hip_bf16.h>

typedef __bf16 bf16_t;
typedef __bf16 bf16x8 __attribute__((ext_vector_type(8)));
typedef float f32x4 __attribute__((ext_vector_type(4)));

#define BM 128
#define BN 128
#define BK 32

#define GLOAD_LDS16(g, l)                                                      \
  __builtin_amdgcn_global_load_lds(                                            \
      (const __attribute__((address_space(1))) void*)(g),                      \
      (__attribute__((address_space(3))) void*)(l), 16, 0, 0)

// C[M][Nc] = A[M][Kd] * Bt[Nc][Kd]^T, bf16 inputs, f32 accum.
// u-only LISTA iteration: u' = soft_thresh(u - S@u) + Wx
// mode 0: WxOut = Unext = bf16(acc)                      (Wx GEMM; u1 = Wx)
// mode 1: u=A[idx]; zn=st(u-acc); Unext = bf16(zn + WxIn[idx])
// mode 2: zn=st(u-acc); fused transpose-write to Out[b][k][p]
__global__ __launch_bounds__(256, 4) void gemm_bt_kernel(
    const bf16_t* __restrict__ A, const bf16_t* __restrict__ Bt,
    int M, int Nc, int Kd, int mode,
    const bf16_t* __restrict__ WxIn,
    bf16_t* __restrict__ Unext, bf16_t* __restrict__ WxOut,
    float* __restrict__ Out, const float* __restrict__ thresh_p)
{
  __shared__ __align__(16) char smem[16896];   // staging 16384B; mode-2 T 16896B
  bf16_t* sA = (bf16_t*)smem;
  bf16_t* sB = sA + BM * BK;

  const int tid  = threadIdx.x;
  const int wid  = tid >> 6;
  const int lane = tid & 63;

  // XCD-chunked swizzle: hw bid%8 -> xcd; give each XCD a contiguous logical chunk
  // so the 8 col-tiles sharing one A row-panel land on the same XCD's L2.
  const int per     = gridDim.x >> 3;                  // nwg/8 (nwg % 8 == 0)
  const int logical = (blockIdx.x & 7) * per + (blockIdx.x >> 3);
  const int ntn   = Nc / BN;
  const int tileN = (logical % ntn) * BN;
  const int tileM = (logical / ntn) * BM;

  const int wm = (wid >> 1) * 64;      // wave 2x2 over 128x128, each 64x64
  const int wn = (wid & 1) * 64;
  const int lr = lane & 15;            // fragment row/col
  const int kg = lane >> 4;            // k-group (8 elems)

  f32x4 acc[4][4] = {};

  for (int k0 = 0; k0 < Kd; k0 += BK) {
    __syncthreads();  // previous iter's LDS reads done
    #pragma unroll
    for (int j = 0; j < 2; ++j) {
      const int chunk = j * 4 + wid;              // 0..7, wave-uniform
      const int base  = (chunk << 6) + lane;      // 0..511
      const int row   = base >> 2;                // 0..127
      const int kc    = base & 3;                 // 16B chunk within 64B row
      const int kcs   = kc ^ ((row >> 1) & 3);    // T2: pre-swizzled global source
      const bf16_t* ga = A  + (size_t)(tileM + row) * Kd + k0 + kcs * 8;
      const bf16_t* gb = Bt + (size_t)(tileN + row) * Kd + k0 + kcs * 8;
      GLOAD_LDS16(ga, sA + (chunk << 9));         // LDS dest stays linear
      GLOAD_LDS16(gb, sB + (chunk << 9));
    }
    __syncthreads();  // drains vmcnt + lgkmcnt

    bf16x8 af[4], bfr[4];
    #pragma unroll
    for (int mi = 0; mi < 4; ++mi) {
      const int r  = wm + mi * 16 + lr;
      const int ks = kg ^ ((r >> 1) & 3);
      af[mi] = *reinterpret_cast<const bf16x8*>(sA + r * BK + ks * 8);
    }
    #pragma unroll
    for (int ni = 0; ni < 4; ++ni) {
      const int r  = wn + ni * 16 + lr;
      const int ks = kg ^ ((r >> 1) & 3);
      bfr[ni] = *reinterpret_cast<const bf16x8*>(sB + r * BK + ks * 8);
    }
    #pragma unroll
    for (int mi = 0; mi < 4; ++mi)
      #pragma unroll
      for (int ni = 0; ni < 4; ++ni)
        acc[mi][ni] = __builtin_amdgcn_mfma_f32_16x16x32_bf16(af[mi], bfr[ni], acc[mi][ni], 0, 0, 0);
  }

  const float th = *thresh_p;

  if (mode == 0) {
    #pragma unroll
    for (int mi = 0; mi < 4; ++mi)
      #pragma unroll
      for (int ni = 0; ni < 4; ++ni) {
        const int row0 = tileM + wm + mi * 16 + kg * 4;
        const int col  = tileN + wn + ni * 16 + lr;
        #pragma unroll
        for (int r = 0; r < 4; ++r) {
          const size_t idx = (size_t)(row0 + r) * (size_t)Nc + col;
          const bf16_t w = (bf16_t)acc[mi][ni][r];
          WxOut[idx] = w;
          Unext[idx] = w;                 // u1 = Wx (z0 = 0)
        }
      }
  } else if (mode == 1) {
    #pragma unroll
    for (int mi = 0; mi < 4; ++mi)
      #pragma unroll
      for (int ni = 0; ni < 4; ++ni) {
        const int row0 = tileM + wm + mi * 16 + kg * 4;
        const int col  = tileN + wn + ni * 16 + lr;
        #pragma unroll
        for (int r = 0; r < 4; ++r) {
          const size_t idx = (size_t)(row0 + r) * (size_t)Nc + col;
          const float u  = (float)A[idx];          // Kd == Nc here
          const float wx = (float)WxIn[idx];
          const float t  = u - acc[mi][ni][r];
          const float a  = fabsf(t) - th;
          const float zn = (a > 0.f) ? copysignf(a, t) : 0.f;
          Unext[idx] = (bf16_t)(zn + wx);
        }
      }
  } else {
    // mode 2: zn into acc, then fused transpose-write out[b][k][p]
    #pragma unroll
    for (int mi = 0; mi < 4; ++mi)
      #pragma unroll
      for (int ni = 0; ni < 4; ++ni) {
        const int row0 = tileM + wm + mi * 16 + kg * 4;
        const int col  = tileN + wn + ni * 16 + lr;
        #pragma unroll
        for (int r = 0; r < 4; ++r) {
          const size_t idx = (size_t)(row0 + r) * (size_t)Nc + col;
          const float u = (float)A[idx];
          const float t = u - acc[mi][ni][r];
          const float a = fabsf(t) - th;
          acc[mi][ni][r] = (a > 0.f) ? copysignf(a, t) : 0.f;
        }
      }
    float* T = (float*)smem;                       // [32][132] padded
    const int    bb    = tileM >> 10;              // 128 | 1024 -> b const per block
    const size_t obase = (size_t)bb * 1048576 + (size_t)(tileM & 1023);
    for (int ch = 0; ch < 4; ++ch) {               // 32-col chunks
      __syncthreads();
      if (wn == (ch >> 1) * 64) {                  // owning waves write T[c'][r]
        #pragma unroll
        for (int nj = 0; nj < 2; ++nj) {
          const int ni = (ch & 1) * 2 + nj;
          const int cp = ni * 16 + lr - (ch & 1) * 32;   // 0..31
          #pragma unroll
          for (int mi = 0; mi < 4; ++mi)
            #pragma unroll
            for (int r = 0; r < 4; ++r)
              T[cp * 132 + wm + mi * 16 + kg * 4 + r] = acc[mi][ni][r];
        }
      }
      __syncthreads();
      #pragma unroll
      for (int i = 0; i < 16; ++i) {               // coalesced along p
        const int idx = tid + i * 256;
        const int rr  = idx & 127;
        const int cp  = idx >> 7;
        Out[obase + (size_t)(tileN + ch * 32 + cp) * 1024 + rr] = T[cp * 132 + rr];
      }
    }
  }
}

__global__ void cast_f32_bf16_kernel(const float* __restrict__ src,
                                     bf16_t* __restrict__ dst, int n) {
  int i = blockIdx.x * blockDim.x + threadIdx.x;
  if (i < n) dst[i] = (bf16_t)src[i];
}

// x [B][C=512][P=1024] f32 -> xt [b*1024+p][c] bf16  (32x32 tiled transpose)
__global__ void transpose_cast_x_kernel(const float* __restrict__ x,
                                        bf16_t* __restrict__ xt) {
  __shared__ float t[32][33];
  const int b  = blockIdx.z;
  const int p0 = blockIdx.x * 32;
  const int c0 = blockIdx.y * 32;
  const int tx = threadIdx.x, ty = threadIdx.y;
  #pragma unroll
  for (int i = 0; i < 32; i += 8)
    t[ty + i][tx] = x[((size_t)b * 512 + c0 + ty + i) * 1024 + p0 + tx];
  __syncthreads();
  #pragma unroll
  for (int i = 0; i < 32; i += 8)
    xt[((size_t)b * 1024 + p0 + ty + i) * 512 + c0 + tx] = (bf16_t)t[tx][ty + i];
}

__global__ void dict_norm_kernel(const float* __restrict__ dict,
                                 float* __restrict__ out) {
  const int row = blockIdx.x;       // 1024
  const int tid = threadIdx.x;      // 256
  const float* r = dict + (size_t)row * 512;
  float s = 0.f;
  for (int i = tid; i < 512; i += 256) { float v = r[i]; s += v * v; }
  #pragma unroll
  for (int off = 32; off > 0; off >>= 1) s += __shfl_down(s, off);
  __shared__ float ps[4];
  if ((tid & 63) == 0) ps[tid >> 6] = s;
  __syncthreads();
  const float inv = 1.0f / sqrtf(ps[0] + ps[1] + ps[2] + ps[3]);
  for (int i = tid; i < 512; i += 256) out[(size_t)row * 512 + i] = r[i] * inv;
}

extern "C" void kernel_launch(void* const* d_in, const int* in_sizes, int n_in,
                              void* d_out, int out_size, void* d_ws, size_t ws_size,
                              hipStream_t stream) {
  const float* x      = (const float*)d_in[0];  // [32,512,32,32]
  const float* dict   = (const float*)d_in[1];  // [1024,512]
  const float* W      = (const float*)d_in[2];  // [1024,512]
  const float* S      = (const float*)d_in[3];  // [1024,1024]
  const float* thresh = (const float*)d_in[4];  // scalar

  float* out = (float*)d_out;

  char* ws = (char*)d_ws;
  bf16_t* uA   = (bf16_t*)ws;                     //  67,108,864 B [32768][1024]
  bf16_t* uB   = (bf16_t*)(ws + 67108864);        //  67,108,864 B
  bf16_t* WxBf = (bf16_t*)(ws + 134217728);       //  67,108,864 B
  bf16_t* xt   = (bf16_t*)(ws + 201326592);       //  33,554,432 B [32768][512]
  bf16_t* Wbf  = (bf16_t*)(ws + 234881024);       //   1,048,576 B
  bf16_t* Sbf  = (bf16_t*)(ws + 235929600);       //   2,097,152 B (end 238,026,752)

  float* dnorm = out + 33554432;                  // dict_norm region (disjoint)

  cast_f32_bf16_kernel<<<dim3(2048), dim3(256), 0, stream>>>(W, Wbf, 524288);
  cast_f32_bf16_kernel<<<dim3(4096), dim3(256), 0, stream>>>(S, Sbf, 1048576);
  transpose_cast_x_kernel<<<dim3(32, 16, 32), dim3(32, 8), 0, stream>>>(x, xt);
  dict_norm_kernel<<<dim3(1024), dim3(256), 0, stream>>>(dict, dnorm);

  // Wx_t = x_t @ W^T  -> WxBf, uA (= u1)
  gemm_bt_kernel<<<dim3(2048), dim3(256), 0, stream>>>(
      xt, Wbf, 32768, 1024, 512, 0, nullptr, uA, WxBf, nullptr, thresh);

  // steps 1..4: u' = soft_thresh(u - S@u) + Wx
  bf16_t* uc = uA; bf16_t* un = uB;
  for (int s = 0; s < 4; ++s) {
    gemm_bt_kernel<<<dim3(2048), dim3(256), 0, stream>>>(
        uc, Sbf, 32768, 1024, 1024, 1, WxBf, un, nullptr, nullptr, thresh);
    bf16_t* tmp = uc; uc = un; un = tmp;
  }
  // step 5: z = soft_thresh(u - S@u), fused transpose to out[b][k][p]
  gemm_bt_kernel<<<dim3(2048), dim3(256), 0, stream>>>(
      uc, Sbf, 32768, 1024, 1024, 2, nullptr, nullptr, nullptr, out, thresh);
}

// Round 3
// 626.298 us; speedup vs baseline: 2.2378x; 1.0139x over previous
//
#include <hip/hip_runtime.h>
#include <hip/hip_bf16.h>

typedef __bf16 bf16_t;
typedef __bf16 bf16x8 __attribute__((ext_vector_type(8)));
typedef float f32x4 __attribute__((ext_vector_type(4)));

#define GLOAD_LDS16(g, l)                                                      \
  __builtin_amdgcn_global_load_lds(                                            \
      (const __attribute__((address_space(1))) void*)(g),                      \
      (__attribute__((address_space(3))) void*)(l), 16, 0, 0)

#define MFMA(a, b, c) __builtin_amdgcn_mfma_f32_16x16x32_bf16((a), (b), (c), 0, 0, 0)

// ---------------------------------------------------------------------------
// 256x256-tile, 8-wave, 4-phase-per-K-tile GEMM (8-phase template, T2-T5).
// C[M][1024] = A[M][Kd] * Bt[1024][Kd]^T, bf16 in, f32 accum.
// Waves: 2(M)x4(N); per-wave output 128x64 (M_rep=8, N_rep=4), BK=64 (2 ks).
// LDS: 2 bufs x (A 32KB + B 32KB) = 128KB. Per matrix: 2 sub-tiles [256][32]
// (ks=0,1), row stride 64B, 16B units XOR-swizzled by ((row>>1)&3) — the
// round-2 measured-conflict-free scheme. global_load_lds dest stays linear;
// the swizzle is applied to the GLOBAL source column (m173 pattern).
//
// Phases per K-tile t (quadrants of the per-wave 8x4 acc):
//   P0 (mi 0-3 x ni 0-1): reads A-half0 (rows bit6==0) + B-half0 (bit5==0)
//   P1 (mi 0-3 x ni 2-3): reads B-half1
//   P2 (mi 4-7 x ni 2-3): reads A-half1
//   P3 (mi 4-7 x ni 0-1): all in regs
// Stage issue at iter t (into buf nxt, tile t+1), matching consumption order:
//   P0: A-h0, P1: B-g0, P2: B-g1, P3: A-h1    (2 loads each per wave)
// vmcnt accounting (loads, steady state; wait covers NEXT phase's ds_read):
//   end P3: {A0,B0,B1,A1}=8 -> vmcnt(4): A0,B0 landed   (P0 reads them)
//   end P0: {B1,A1,A0'}=6   -> vmcnt(4): B1 landed      (P1)
//   end P1: {A1,A0',B0'}=6  -> vmcnt(4): A1 landed      (P2)
//   end P2: no wait (P3 reads nothing new)
// Last iter stages tile 0 again (harmless, keeps loop uniform + in-bounds).
//
// mode 0: UnextOrWx[idx] = bf16(acc)            (Wx GEMM; step1 reads Wx as u)
// mode 1: u=A[idx]; UnextOrWx[idx] = bf16(soft_thresh(u-acc) + WxIn[idx])
// mode 2: zn = soft_thresh(A[idx]-acc); fused transpose-write Out[b][k][p]
// ---------------------------------------------------------------------------
__global__ __launch_bounds__(512, 2) void gemm8_kernel(
    const bf16_t* __restrict__ A, const bf16_t* __restrict__ Bt,
    int Kd, int mode,
    const bf16_t* __restrict__ WxIn, bf16_t* __restrict__ UnextOrWx,
    float* __restrict__ Out, const float* __restrict__ thresh_p)
{
  __shared__ __align__(16) char smem[131072];
  bf16_t* lds = (bf16_t*)smem;     // elem offsets: buf*32768, B at +16384

  const int tid  = threadIdx.x;
  const int wid  = tid >> 6, lane = tid & 63;
  const int wr = wid >> 2, wc = wid & 3;
  const int lr = lane & 15, kg = lane >> 4;
  const int l2 = lane >> 2, l4 = lane & 3;     // stage: row-in-16 / 16B-unit

  // XCD-chunked swizzle (512 % 8 == 0): N-fastest so one XCD's 64 logical
  // blocks = 16 M-panels x all 4 N-tiles -> S resident + A-panel shared in L2.
  const int per     = gridDim.x >> 3;
  const int logical = (blockIdx.x & 7) * per + (blockIdx.x >> 3);
  const int tileN = (logical & 3) << 8;
  const int tileM = (logical >> 2) << 8;

  const int NT = Kd >> 6;

  auto stageA = [&](int t, int h, int buf) {
    const int k0 = t << 6;
    #pragma unroll
    for (int l = 0; l < 2; ++l) {
      const int c  = l * 8 + wid;               // chunk 0..15
      const int ks = c >> 3, c3 = c & 7, q = c3 >> 2;
      const int R  = q * 128 + h * 64 + (c3 & 3) * 16 + l2;
      const int kcs = l4 ^ ((R >> 1) & 3);      // pre-swizzled global source
      const bf16_t* src = A + (size_t)(tileM + R) * Kd + k0 + ks * 32 + kcs * 8;
      bf16_t* dst = lds + buf * 32768 + ks * 8192 + q * 4096 + h * 2048 + (c3 & 3) * 512;
      GLOAD_LDS16(src, dst);
    }
  };
  auto stageB = [&](int t, int g, int buf) {
    const int k0 = t << 6;
    #pragma unroll
    for (int l = 0; l < 2; ++l) {
      const int c  = l * 8 + wid;
      const int ks = c >> 3, c3 = c & 7, q2 = c3 >> 1;
      const int R  = q2 * 64 + g * 32 + (c3 & 1) * 16 + l2;
      const int kcs = l4 ^ ((R >> 1) & 3);
      const bf16_t* src = Bt + (size_t)(tileN + R) * Kd + k0 + ks * 32 + kcs * 8;
      bf16_t* dst = lds + buf * 32768 + 16384 + ks * 8192 + q2 * 2048 + g * 1024 + (c3 & 1) * 512;
      GLOAD_LDS16(src, dst);
    }
  };
  auto readA = [&](int mi, int ks, int buf) -> bf16x8 {
    const int R = wr * 128 + mi * 16 + lr;
    return *(const bf16x8*)(lds + buf * 32768 + ks * 8192 + R * 32 + ((kg ^ ((R >> 1) & 3)) << 3));
  };
  auto readB = [&](int ni, int ks, int buf) -> bf16x8 {
    const int R = wc * 64 + ni * 16 + lr;
    return *(const bf16x8*)(lds + buf * 32768 + 16384 + ks * 8192 + R * 32 + ((kg ^ ((R >> 1) & 3)) << 3));
  };

  f32x4 acc[8][4] = {};
  bf16x8 af[4][2], b0[2][2], b1[2][2];

  // Prologue: tile 0 -> buf 0, same issue order as steady state.
  stageA(0, 0, 0); stageB(0, 0, 0); stageB(0, 1, 0); stageA(0, 1, 0);
  asm volatile("s_waitcnt vmcnt(4)" ::: "memory");
  __builtin_amdgcn_s_barrier();

  for (int t = 0; t < NT; ++t) {
    const int cur = t & 1, nxt = cur ^ 1;
    const int tn = (t + 1 == NT) ? 0 : t + 1;

    // ---- P0: (h0, g0)
    #pragma unroll
    for (int mi = 0; mi < 4; ++mi) { af[mi][0] = readA(mi, 0, cur); af[mi][1] = readA(mi, 1, cur); }
    #pragma unroll
    for (int ni = 0; ni < 2; ++ni) { b0[ni][0] = readB(ni, 0, cur); b0[ni][1] = readB(ni, 1, cur); }
    stageA(tn, 0, nxt);
    __builtin_amdgcn_s_barrier();
    asm volatile("s_waitcnt lgkmcnt(0)" ::: "memory");
    __builtin_amdgcn_sched_barrier(0);
    __builtin_amdgcn_s_setprio(1);
    #pragma unroll
    for (int mi = 0; mi < 4; ++mi)
      #pragma unroll
      for (int ni = 0; ni < 2; ++ni) {
        acc[mi][ni] = MFMA(af[mi][0], b0[ni][0], acc[mi][ni]);
        acc[mi][ni] = MFMA(af[mi][1], b0[ni][1], acc[mi][ni]);
      }
    __builtin_amdgcn_s_setprio(0);
    asm volatile("s_waitcnt vmcnt(4)" ::: "memory");
    __builtin_amdgcn_s_barrier();

    // ---- P1: (h0, g1)
    #pragma unroll
    for (int ni = 0; ni < 2; ++ni) { b1[ni][0] = readB(ni + 2, 0, cur); b1[ni][1] = readB(ni + 2, 1, cur); }
    stageB(tn, 0, nxt);
    __builtin_amdgcn_s_barrier();
    asm volatile("s_waitcnt lgkmcnt(0)" ::: "memory");
    __builtin_amdgcn_sched_barrier(0);
    __builtin_amdgcn_s_setprio(1);
    #pragma unroll
    for (int mi = 0; mi < 4; ++mi)
      #pragma unroll
      for (int ni = 0; ni < 2; ++ni) {
        acc[mi][ni + 2] = MFMA(af[mi][0], b1[ni][0], acc[mi][ni + 2]);
        acc[mi][ni + 2] = MFMA(af[mi][1], b1[ni][1], acc[mi][ni + 2]);
      }
    __builtin_amdgcn_s_setprio(0);
    asm volatile("s_waitcnt vmcnt(4)" ::: "memory");
    __builtin_amdgcn_s_barrier();

    // ---- P2: (h1, g1)
    #pragma unroll
    for (int mi = 0; mi < 4; ++mi) { af[mi][0] = readA(mi + 4, 0, cur); af[mi][1] = readA(mi + 4, 1, cur); }
    stageB(tn, 1, nxt);
    __builtin_amdgcn_s_barrier();
    asm volatile("s_waitcnt lgkmcnt(0)" ::: "memory");
    __builtin_amdgcn_sched_barrier(0);
    __builtin_amdgcn_s_setprio(1);
    #pragma unroll
    for (int mi = 0; mi < 4; ++mi)
      #pragma unroll
      for (int ni = 0; ni < 2; ++ni) {
        acc[mi + 4][ni + 2] = MFMA(af[mi][0], b1[ni][0], acc[mi + 4][ni + 2]);
        acc[mi + 4][ni + 2] = MFMA(af[mi][1], b1[ni][1], acc[mi + 4][ni + 2]);
      }
    __builtin_amdgcn_s_setprio(0);
    __builtin_amdgcn_s_barrier();              // no vmcnt: P3 reads nothing new

    // ---- P3: (h1, g0)
    stageA(tn, 1, nxt);
    __builtin_amdgcn_s_barrier();
    __builtin_amdgcn_s_setprio(1);
    #pragma unroll
    for (int mi = 0; mi < 4; ++mi)
      #pragma unroll
      for (int ni = 0; ni < 2; ++ni) {
        acc[mi + 4][ni] = MFMA(af[mi][0], b0[ni][0], acc[mi + 4][ni]);
        acc[mi + 4][ni] = MFMA(af[mi][1], b0[ni][1], acc[mi + 4][ni]);
      }
    __builtin_amdgcn_s_setprio(0);
    asm volatile("s_waitcnt vmcnt(4)" ::: "memory");
    __builtin_amdgcn_s_barrier();
  }

  const float th = *thresh_p;

  if (mode == 0) {
    #pragma unroll
    for (int mi = 0; mi < 8; ++mi)
      #pragma unroll
      for (int ni = 0; ni < 4; ++ni) {
        const int row0 = tileM + wr * 128 + mi * 16 + kg * 4;
        const int col  = tileN + wc * 64 + ni * 16 + lr;
        #pragma unroll
        for (int r = 0; r < 4; ++r)
          UnextOrWx[(size_t)(row0 + r) * 1024 + col] = (bf16_t)acc[mi][ni][r];
      }
  } else if (mode == 1) {
    #pragma unroll
    for (int mi = 0; mi < 8; ++mi)
      #pragma unroll
      for (int ni = 0; ni < 4; ++ni) {
        const int row0 = tileM + wr * 128 + mi * 16 + kg * 4;
        const int col  = tileN + wc * 64 + ni * 16 + lr;
        #pragma unroll
        for (int r = 0; r < 4; ++r) {
          const size_t idx = (size_t)(row0 + r) * 1024 + col;
          const float u  = (float)A[idx];
          const float wx = (float)WxIn[idx];
          const float tt = u - acc[mi][ni][r];
          const float a  = fabsf(tt) - th;
          const float zn = (a > 0.f) ? copysignf(a, tt) : 0.f;
          UnextOrWx[idx] = (bf16_t)(zn + wx);
        }
      }
  } else {
    // mode 2: zn in place, then fused transpose via LDS (reused after drain)
    #pragma unroll
    for (int mi = 0; mi < 8; ++mi)
      #pragma unroll
      for (int ni = 0; ni < 4; ++ni) {
        const int row0 = tileM + wr * 128 + mi * 16 + kg * 4;
        const int col  = tileN + wc * 64 + ni * 16 + lr;
        #pragma unroll
        for (int r = 0; r < 4; ++r) {
          const size_t idx = (size_t)(row0 + r) * 1024 + col;
          const float u  = (float)A[idx];
          const float tt = u - acc[mi][ni][r];
          const float a  = fabsf(tt) - th;
          acc[mi][ni][r] = (a > 0.f) ? copysignf(a, tt) : 0.f;
        }
      }
    asm volatile("s_waitcnt vmcnt(0)" ::: "memory");   // stray garbage stages
    __syncthreads();
    float* T = (float*)smem;                           // [32][260] f32
    const int    bb    = tileM >> 10;
    const size_t obase = (size_t)bb * 1048576 + (size_t)(tileM & 1023);
    for (int ch = 0; ch < 8; ++ch) {                   // 32-col chunks
      if (ch) __syncthreads();
      if (wc == (ch >> 1)) {
        #pragma unroll
        for (int nj = 0; nj < 2; ++nj) {
          const int ni = (ch & 1) * 2 + nj;
          const int cp = nj * 16 + lr;
          #pragma unroll
          for (int mi = 0; mi < 8; ++mi)
            #pragma unroll
            for (int r = 0; r < 4; ++r)
              T[cp * 260 + wr * 128 + mi * 16 + kg * 4 + r] = acc[mi][ni][r];
        }
      }
      __syncthreads();
      #pragma unroll
      for (int j = 0; j < 4; ++j) {
        const int f  = tid + j * 512;                  // f32x4 id 0..2047
        const int cp = f >> 6;
        const int R4 = (f & 63) * 4;
        const f32x4 v = *(const f32x4*)&T[cp * 260 + R4];
        *(f32x4*)&Out[obase + (size_t)(tileN + ch * 32 + cp) * 1024 + R4] = v;
      }
    }
  }
}

__global__ void cast_f32_bf16_kernel(const float* __restrict__ src,
                                     bf16_t* __restrict__ dst, int n) {
  int i = blockIdx.x * blockDim.x + threadIdx.x;
  if (i < n) dst[i] = (bf16_t)src[i];
}

// x [B][C=512][P=1024] f32 -> xt [b*1024+p][c] bf16  (32x32 tiled transpose)
__global__ void transpose_cast_x_kernel(const float* __restrict__ x,
                                        bf16_t* __restrict__ xt) {
  __shared__ float t[32][33];
  const int b  = blockIdx.z;
  const int p0 = blockIdx.x * 32;
  const int c0 = blockIdx.y * 32;
  const int tx = threadIdx.x, ty = threadIdx.y;
  #pragma unroll
  for (int i = 0; i < 32; i += 8)
    t[ty + i][tx] = x[((size_t)b * 512 + c0 + ty + i) * 1024 + p0 + tx];
  __syncthreads();
  #pragma unroll
  for (int i = 0; i < 32; i += 8)
    xt[((size_t)b * 1024 + p0 + ty + i) * 512 + c0 + tx] = (bf16_t)t[tx][ty + i];
}

__global__ void dict_norm_kernel(const float* __restrict__ dict,
                                 float* __restrict__ out) {
  const int row = blockIdx.x;       // 1024
  const int tid = threadIdx.x;      // 256
  const float* r = dict + (size_t)row * 512;
  float s = 0.f;
  for (int i = tid; i < 512; i += 256) { float v = r[i]; s += v * v; }
  #pragma unroll
  for (int off = 32; off > 0; off >>= 1) s += __shfl_down(s, off);
  __shared__ float ps[4];
  if ((tid & 63) == 0) ps[tid >> 6] = s;
  __syncthreads();
  const float inv = 1.0f / sqrtf(ps[0] + ps[1] + ps[2] + ps[3]);
  for (int i = tid; i < 512; i += 256) out[(size_t)row * 512 + i] = r[i] * inv;
}

extern "C" void kernel_launch(void* const* d_in, const int* in_sizes, int n_in,
                              void* d_out, int out_size, void* d_ws, size_t ws_size,
                              hipStream_t stream) {
  const float* x      = (const float*)d_in[0];  // [32,512,32,32]
  const float* dict   = (const float*)d_in[1];  // [1024,512]
  const float* W      = (const float*)d_in[2];  // [1024,512]
  const float* S      = (const float*)d_in[3];  // [1024,1024]
  const float* thresh = (const float*)d_in[4];  // scalar

  float* out = (float*)d_out;

  char* ws = (char*)d_ws;
  bf16_t* uA   = (bf16_t*)ws;                     //  67,108,864 B [32768][1024]
  bf16_t* uB   = (bf16_t*)(ws + 67108864);        //  67,108,864 B
  bf16_t* WxBf = (bf16_t*)(ws + 134217728);       //  67,108,864 B
  bf16_t* xt   = (bf16_t*)(ws + 201326592);       //  33,554,432 B [32768][512]
  bf16_t* Wbf  = (bf16_t*)(ws + 234881024);       //   1,048,576 B
  bf16_t* Sbf  = (bf16_t*)(ws + 235929600);       //   2,097,152 B (end 238,026,752)

  float* dnorm = out + 33554432;                  // dict_norm region (disjoint)

  cast_f32_bf16_kernel<<<dim3(2048), dim3(256), 0, stream>>>(W, Wbf, 524288);
  cast_f32_bf16_kernel<<<dim3(4096), dim3(256), 0, stream>>>(S, Sbf, 1048576);
  transpose_cast_x_kernel<<<dim3(32, 16, 32), dim3(32, 8), 0, stream>>>(x, xt);
  dict_norm_kernel<<<dim3(1024), dim3(256), 0, stream>>>(dict, dnorm);

  // Wx_t = x_t @ W^T  -> WxBf  (u1 == Wx, read directly by step 1)
  gemm8_kernel<<<dim3(512), dim3(512), 0, stream>>>(
      xt, Wbf, 512, 0, nullptr, WxBf, nullptr, thresh);

  // steps 1..4: u' = soft_thresh(u - S@u) + Wx
  bf16_t* uc = WxBf; bf16_t* un = uA;
  for (int s = 0; s < 4; ++s) {
    gemm8_kernel<<<dim3(512), dim3(512), 0, stream>>>(
        uc, Sbf, 1024, 1, WxBf, un, nullptr, thresh);
    uc = un;
    un = (uc == uA) ? uB : uA;
  }
  // step 5: z = soft_thresh(u - S@u), fused transpose to out[b][k][p]
  gemm8_kernel<<<dim3(512), dim3(512), 0, stream>>>(
      uc, Sbf, 1024, 2, nullptr, nullptr, out, thresh);
}